// Round 2
// baseline (5339.057 us; speedup 1.0000x reference)
//
#include <hip/hip_runtime.h>

#define NUSERS 100000
#define NITEMS 200000
#define NNODES 300000
#define DIM 64
#define NEDGES 2000000
#define NLAYERS 3

// ---------------------------------------------------------------------------
// init: x_cur = concat(user_emb, item_emb); acc (=d_out) = same
// vectorized as float4 (DIM=64 -> 16 float4 per node)
// ---------------------------------------------------------------------------
__global__ void init_kernel(const float4* __restrict__ user,
                            const float4* __restrict__ item,
                            float4* __restrict__ x,
                            float4* __restrict__ acc) {
    int i = blockIdx.x * blockDim.x + threadIdx.x;
    const int n_user4 = NUSERS * (DIM / 4);
    const int n4 = NNODES * (DIM / 4);
    if (i < n4) {
        float4 v = (i < n_user4) ? user[i] : item[i - n_user4];
        x[i] = v;
        acc[i] = v;
    }
}

// ---------------------------------------------------------------------------
// scatter: for each edge e: x_next[src[e]] += x_cur[dst[e]] * vals[e]
// 16 lanes per edge; each lane loads one float4 (16B) of the dst row and
// issues 4 hardware f32 atomics into the src row.
// ---------------------------------------------------------------------------
__global__ void scatter_kernel(const float* __restrict__ xcur,
                               const float* __restrict__ vals,
                               const int* __restrict__ src,
                               const int* __restrict__ dst,
                               float* __restrict__ xnext) {
    int t = blockIdx.x * blockDim.x + threadIdx.x;
    int e = t >> 4;          // edge index
    int lane = t & 15;       // 0..15, covers 4 floats each
    if (e < NEDGES) {
        int s = src[e];
        int d = dst[e];
        float v = vals[e];
        const float4* row = (const float4*)(xcur + (long)d * DIM);
        float4 m = row[lane];
        float* out = xnext + (long)s * DIM + lane * 4;
        unsafeAtomicAdd(out + 0, m.x * v);
        unsafeAtomicAdd(out + 1, m.y * v);
        unsafeAtomicAdd(out + 2, m.z * v);
        unsafeAtomicAdd(out + 3, m.w * v);
    }
}

// ---------------------------------------------------------------------------
// acc = (acc + x) * scale   (scale = 1.0 for layers 0,1; 0.25 fused on last)
// ---------------------------------------------------------------------------
__global__ void add_scale_kernel(float4* __restrict__ acc,
                                 const float4* __restrict__ x,
                                 float scale) {
    int i = blockIdx.x * blockDim.x + threadIdx.x;
    const int n4 = NNODES * (DIM / 4);
    if (i < n4) {
        float4 a = acc[i];
        float4 b = x[i];
        a.x = (a.x + b.x) * scale;
        a.y = (a.y + b.y) * scale;
        a.z = (a.z + b.z) * scale;
        a.w = (a.w + b.w) * scale;
        acc[i] = a;
    }
}

extern "C" void kernel_launch(void* const* d_in, const int* in_sizes, int n_in,
                              void* d_out, int out_size, void* d_ws, size_t ws_size,
                              hipStream_t stream) {
    const float* user_emb = (const float*)d_in[0];
    const float* item_emb = (const float*)d_in[1];
    const float* edge_vals = (const float*)d_in[2];
    const int* edge_src = (const int*)d_in[3];
    const int* edge_dst = (const int*)d_in[4];
    float* acc = (float*)d_out;

    const size_t node_bytes = (size_t)NNODES * DIM * sizeof(float);
    float* x_cur = (float*)d_ws;
    float* x_next = (float*)((char*)d_ws + node_bytes);

    const int n4 = NNODES * (DIM / 4);
    const int ew_threads = NEDGES * 16;

    dim3 blk(256);
    dim3 grid_nodes((n4 + 255) / 256);
    dim3 grid_edges((ew_threads + 255) / 256);

    init_kernel<<<grid_nodes, blk, 0, stream>>>(
        (const float4*)user_emb, (const float4*)item_emb,
        (float4*)x_cur, (float4*)acc);

    for (int layer = 0; layer < NLAYERS; ++layer) {
        hipMemsetAsync(x_next, 0, node_bytes, stream);
        scatter_kernel<<<grid_edges, blk, 0, stream>>>(
            x_cur, edge_vals, edge_src, edge_dst, x_next);
        float scale = (layer == NLAYERS - 1) ? (1.0f / (NLAYERS + 1)) : 1.0f;
        add_scale_kernel<<<grid_nodes, blk, 0, stream>>>(
            (float4*)acc, (const float4*)x_next, scale);
        // swap buffers
        float* tmp = x_cur; x_cur = x_next; x_next = tmp;
    }
}

// Round 4
// 1389.350 us; speedup vs baseline: 3.8428x; 3.8428x over previous
//
#include <hip/hip_runtime.h>

#define NUSERS 100000
#define NITEMS 200000
#define NNODES 300000
#define DIM 64
#define NEDGES 2000000
#define NLAYERS 3

// ---------------------------------------------------------------------------
// init: x_cur = concat(user_emb, item_emb); acc (=d_out) = same
// ---------------------------------------------------------------------------
__global__ void init_kernel(const float4* __restrict__ user,
                            const float4* __restrict__ item,
                            float4* __restrict__ x,
                            float4* __restrict__ acc) {
    int i = blockIdx.x * blockDim.x + threadIdx.x;
    const int n_user4 = NUSERS * (DIM / 4);
    const int n4 = NNODES * (DIM / 4);
    if (i < n4) {
        float4 v = (i < n_user4) ? user[i] : item[i - n_user4];
        x[i] = v;
        acc[i] = v;
    }
}

// ---------------------------------------------------------------------------
// CSR build step 1: histogram of src
// ---------------------------------------------------------------------------
__global__ void hist_kernel(const int* __restrict__ src,
                            int* __restrict__ counts) {
    int e = blockIdx.x * blockDim.x + threadIdx.x;
    if (e < NEDGES) atomicAdd(&counts[src[e]], 1);
}

// ---------------------------------------------------------------------------
// CSR build step 2: exclusive scan (single block, 256 threads, chunked).
// Writes offsets[0..NNODES] and cursor[0..NNODES-1] (= offsets copy).
// ---------------------------------------------------------------------------
__global__ void scan_kernel(const int* __restrict__ counts,
                            int* __restrict__ offsets,
                            int* __restrict__ cursor) {
    __shared__ int part[256];
    __shared__ int excl[257];
    int t = threadIdx.x;
    const int chunk = (NNODES + 255) / 256;
    int begin = t * chunk;
    int end = begin + chunk; if (end > NNODES) end = NNODES;
    int s = 0;
    for (int i = begin; i < end; ++i) s += counts[i];
    part[t] = s;
    __syncthreads();
    if (t == 0) {
        int run = 0;
        for (int i = 0; i < 256; ++i) { excl[i] = run; run += part[i]; }
        excl[256] = run;
    }
    __syncthreads();
    int run = excl[t];
    for (int i = begin; i < end; ++i) {
        offsets[i] = run;
        cursor[i] = run;
        run += counts[i];
    }
    if (t == 255) offsets[NNODES] = excl[256];
}

// ---------------------------------------------------------------------------
// CSR build step 3: scatter edges into src-sorted order
// ---------------------------------------------------------------------------
__global__ void fill_kernel(const int* __restrict__ src,
                            const int* __restrict__ dst,
                            const float* __restrict__ vals,
                            int* __restrict__ cursor,
                            int* __restrict__ sdst,
                            float* __restrict__ sval) {
    int e = blockIdx.x * blockDim.x + threadIdx.x;
    if (e < NEDGES) {
        int p = atomicAdd(&cursor[src[e]], 1);
        sdst[p] = dst[e];
        sval[p] = vals[e];
    }
}

// ---------------------------------------------------------------------------
// Per-layer gather: 16 lanes per node (lane owns one float4 column slice).
// x_next[n] = sum over CSR edges of x_cur[dst]*val ; acc = (acc + sum)*scale
// Last layer: skip x_next store (write_next = 0).
// ---------------------------------------------------------------------------
__global__ void gather_kernel(const float* __restrict__ xcur,
                              const int* __restrict__ offsets,
                              const int* __restrict__ sdst,
                              const float* __restrict__ sval,
                              float* __restrict__ xnext,
                              float* __restrict__ acc,
                              float scale, int write_next) {
    int t = blockIdx.x * blockDim.x + threadIdx.x;
    int n = t >> 4;
    int lane = t & 15;
    if (n >= NNODES) return;
    int b = offsets[n];
    int e_end = offsets[n + 1];
    float4 sum = make_float4(0.f, 0.f, 0.f, 0.f);
    for (int e = b; e < e_end; ++e) {
        int d = sdst[e];
        float v = sval[e];
        const float4 r = *(const float4*)(xcur + (size_t)d * DIM + lane * 4);
        sum.x += r.x * v;
        sum.y += r.y * v;
        sum.z += r.z * v;
        sum.w += r.w * v;
    }
    size_t o = (size_t)n * DIM + lane * 4;
    if (write_next) *(float4*)(xnext + o) = sum;
    float4 a = *(const float4*)(acc + o);
    a.x = (a.x + sum.x) * scale;
    a.y = (a.y + sum.y) * scale;
    a.z = (a.z + sum.z) * scale;
    a.w = (a.w + sum.w) * scale;
    *(float4*)(acc + o) = a;
}

extern "C" void kernel_launch(void* const* d_in, const int* in_sizes, int n_in,
                              void* d_out, int out_size, void* d_ws, size_t ws_size,
                              hipStream_t stream) {
    const float* user_emb = (const float*)d_in[0];
    const float* item_emb = (const float*)d_in[1];
    const float* edge_vals = (const float*)d_in[2];
    const int* edge_src = (const int*)d_in[3];
    const int* edge_dst = (const int*)d_in[4];
    float* acc = (float*)d_out;

    // ---- workspace layout (bytes) ----
    const size_t node_bytes = (size_t)NNODES * DIM * sizeof(float); // 76.8 MB
    char* ws = (char*)d_ws;
    float* x_cur  = (float*)(ws);
    float* x_next = (float*)(ws + node_bytes);
    int* offsets  = (int*)(ws + 2 * node_bytes);                    // NNODES+1
    int* cursor   = (int*)(ws + 2 * node_bytes + 1200016);          // NNODES
    int* sdst     = (int*)(ws + 2 * node_bytes + 1200016 + 1200000);// NEDGES
    float* sval   = (float*)(ws + 2 * node_bytes + 1200016 + 1200000
                             + (size_t)NEDGES * 4);                 // NEDGES
    // counts aliases sval's region (dead before sval is written)
    int* counts   = (int*)sval;

    const int n4 = NNODES * (DIM / 4);
    dim3 blk(256);
    dim3 grid_nodes4((n4 + 255) / 256);
    dim3 grid_edges((NEDGES + 255) / 256);
    dim3 grid_gather((NNODES * 16 + 255) / 256);

    init_kernel<<<grid_nodes4, blk, 0, stream>>>(
        (const float4*)user_emb, (const float4*)item_emb,
        (float4*)x_cur, (float4*)acc);

    hipMemsetAsync(counts, 0, (size_t)NNODES * sizeof(int), stream);
    hist_kernel<<<grid_edges, blk, 0, stream>>>(edge_src, counts);
    scan_kernel<<<1, blk, 0, stream>>>(counts, offsets, cursor);
    fill_kernel<<<grid_edges, blk, 0, stream>>>(edge_src, edge_dst, edge_vals,
                                                cursor, sdst, sval);

    for (int layer = 0; layer < NLAYERS; ++layer) {
        float scale = (layer == NLAYERS - 1) ? (1.0f / (NLAYERS + 1)) : 1.0f;
        int write_next = (layer < NLAYERS - 1) ? 1 : 0;
        gather_kernel<<<grid_gather, blk, 0, stream>>>(
            x_cur, offsets, sdst, sval, x_next, acc, scale, write_next);
        float* tmp = x_cur; x_cur = x_next; x_next = tmp;
    }
}

// Round 7
// 727.023 us; speedup vs baseline: 7.3437x; 1.9110x over previous
//
#include <hip/hip_runtime.h>

#define NUSERS 100000
#define NITEMS 200000
#define NNODES 300000
#define DIM 64
#define NEDGES 2000000
#define NLAYERS 3
#define SCAN_NB ((NNODES + 255) / 256)   // 1172

// ---------------------------------------------------------------------------
// init: x_cur = concat(user_emb, item_emb); acc (=d_out) = same
// ---------------------------------------------------------------------------
__global__ void init_kernel(const float4* __restrict__ user,
                            const float4* __restrict__ item,
                            float4* __restrict__ x,
                            float4* __restrict__ acc) {
    int i = blockIdx.x * blockDim.x + threadIdx.x;
    const int n_user4 = NUSERS * (DIM / 4);
    const int n4 = NNODES * (DIM / 4);
    if (i < n4) {
        float4 v = (i < n_user4) ? user[i] : item[i - n_user4];
        x[i] = v;
        acc[i] = v;
    }
}

// ---------------------------------------------------------------------------
// CSR build step 1: histogram of src
// ---------------------------------------------------------------------------
__global__ void hist_kernel(const int* __restrict__ src,
                            int* __restrict__ counts) {
    int e = blockIdx.x * blockDim.x + threadIdx.x;
    if (e < NEDGES) atomicAdd(&counts[src[e]], 1);
}

// ---------------------------------------------------------------------------
// scan phase A: per-block exclusive scan of 256 counts -> offsets (local),
// plus one block total per block.
// ---------------------------------------------------------------------------
__global__ void scan_blocks_kernel(const int* __restrict__ counts,
                                   int* __restrict__ offsets,
                                   int* __restrict__ blocksums) {
    __shared__ int tmp[256];
    int t = threadIdx.x;
    int i = blockIdx.x * 256 + t;
    int v = (i < NNODES) ? counts[i] : 0;
    tmp[t] = v;
    __syncthreads();
    for (int off = 1; off < 256; off <<= 1) {
        int y = (t >= off) ? tmp[t - off] : 0;
        __syncthreads();
        tmp[t] += y;
        __syncthreads();
    }
    int incl = tmp[t];
    if (i < NNODES) offsets[i] = incl - v;   // exclusive, local to block
    if (t == 255) blocksums[blockIdx.x] = incl;
}

// ---------------------------------------------------------------------------
// scan phase B: single block exclusive-scans the SCAN_NB blocksums in place
// ---------------------------------------------------------------------------
__global__ void scan_top_kernel(int* __restrict__ blocksums) {
    __shared__ int part[256];
    __shared__ int excl[256];
    int t = threadIdx.x;
    const int chunk = (SCAN_NB + 255) / 256;   // 5
    int b0 = t * chunk;
    int b1 = b0 + chunk; if (b1 > SCAN_NB) b1 = SCAN_NB;
    int s = 0;
    for (int i = b0; i < b1; ++i) s += blocksums[i];
    part[t] = s;
    __syncthreads();
    if (t == 0) {
        int run = 0;
        for (int i = 0; i < 256; ++i) { excl[i] = run; run += part[i]; }
    }
    __syncthreads();
    int run = excl[t];
    for (int i = b0; i < b1; ++i) {
        int v = blocksums[i];
        blocksums[i] = run;
        run += v;
    }
}

// ---------------------------------------------------------------------------
// scan phase C: offsets += block base; cursor = offsets; offsets[NNODES]=NEDGES
// ---------------------------------------------------------------------------
__global__ void add_base_kernel(const int* __restrict__ blocksums,
                                int* __restrict__ offsets,
                                int* __restrict__ cursor) {
    int i = blockIdx.x * 256 + threadIdx.x;
    if (i < NNODES) {
        int o = offsets[i] + blocksums[blockIdx.x];
        offsets[i] = o;
        cursor[i] = o;
    }
    if (i == 0) offsets[NNODES] = NEDGES;
}

// ---------------------------------------------------------------------------
// CSR build step 3: scatter edges into src-sorted order (interleaved int2:
// .x = dst index, .y = val bits) -> one 8B store per edge
// ---------------------------------------------------------------------------
__global__ void fill_kernel(const int* __restrict__ src,
                            const int* __restrict__ dst,
                            const float* __restrict__ vals,
                            int* __restrict__ cursor,
                            int2* __restrict__ edata) {
    int e = blockIdx.x * blockDim.x + threadIdx.x;
    if (e < NEDGES) {
        int p = atomicAdd(&cursor[src[e]], 1);
        int2 ed;
        ed.x = dst[e];
        ed.y = __float_as_int(vals[e]);
        edata[p] = ed;
    }
}

// ---------------------------------------------------------------------------
// Per-layer gather: 16 lanes per node (lane owns one float4 column slice).
// x_next[n] = sum over CSR edges of x_cur[dst]*val ; acc = (acc + sum)*scale
// Last layer: skip x_next store (write_next = 0).
// ---------------------------------------------------------------------------
__global__ void gather_kernel(const float* __restrict__ xcur,
                              const int* __restrict__ offsets,
                              const int2* __restrict__ edata,
                              float* __restrict__ xnext,
                              float* __restrict__ acc,
                              float scale, int write_next) {
    int t = blockIdx.x * blockDim.x + threadIdx.x;
    int n = t >> 4;
    int lane = t & 15;
    if (n >= NNODES) return;
    int b = offsets[n];
    int e_end = offsets[n + 1];
    float4 sum = make_float4(0.f, 0.f, 0.f, 0.f);
    for (int e = b; e < e_end; ++e) {
        int2 ed = edata[e];
        float v = __int_as_float(ed.y);
        const float4 r = *(const float4*)(xcur + (size_t)ed.x * DIM + lane * 4);
        sum.x += r.x * v;
        sum.y += r.y * v;
        sum.z += r.z * v;
        sum.w += r.w * v;
    }
    size_t o = (size_t)n * DIM + lane * 4;
    if (write_next) *(float4*)(xnext + o) = sum;
    float4 a = *(const float4*)(acc + o);
    a.x = (a.x + sum.x) * scale;
    a.y = (a.y + sum.y) * scale;
    a.z = (a.z + sum.z) * scale;
    a.w = (a.w + sum.w) * scale;
    *(float4*)(acc + o) = a;
}

extern "C" void kernel_launch(void* const* d_in, const int* in_sizes, int n_in,
                              void* d_out, int out_size, void* d_ws, size_t ws_size,
                              hipStream_t stream) {
    const float* user_emb = (const float*)d_in[0];
    const float* item_emb = (const float*)d_in[1];
    const float* edge_vals = (const float*)d_in[2];
    const int* edge_src = (const int*)d_in[3];
    const int* edge_dst = (const int*)d_in[4];
    float* acc = (float*)d_out;

    // ---- workspace layout (bytes) ----
    const size_t node_bytes = (size_t)NNODES * DIM * sizeof(float); // 76.8 MB
    char* ws = (char*)d_ws;
    float* x_cur   = (float*)(ws);
    float* x_next  = (float*)(ws + node_bytes);
    char* p        = ws + 2 * node_bytes;
    int* offsets   = (int*)p;                 p += (size_t)(NNODES + 1) * 4 + 12; // keep 16B align
    int* cursor    = (int*)p;                 p += (size_t)NNODES * 4;
    int* blocksums = (int*)p;                 p += (size_t)SCAN_NB * 4 + 16;
    int2* edata    = (int2*)p;                p += (size_t)NEDGES * 8;            // 16 MB
    // counts aliases edata's first half (dead before edata is written)
    int* counts    = (int*)edata;

    const int n4 = NNODES * (DIM / 4);
    dim3 blk(256);
    dim3 grid_nodes4((n4 + 255) / 256);
    dim3 grid_edges((NEDGES + 255) / 256);
    dim3 grid_scan(SCAN_NB);
    dim3 grid_gather((NNODES * 16 + 255) / 256);

    init_kernel<<<grid_nodes4, blk, 0, stream>>>(
        (const float4*)user_emb, (const float4*)item_emb,
        (float4*)x_cur, (float4*)acc);

    hipMemsetAsync(counts, 0, (size_t)NNODES * sizeof(int), stream);
    hist_kernel<<<grid_edges, blk, 0, stream>>>(edge_src, counts);
    scan_blocks_kernel<<<grid_scan, blk, 0, stream>>>(counts, offsets, blocksums);
    scan_top_kernel<<<1, blk, 0, stream>>>(blocksums);
    add_base_kernel<<<grid_scan, blk, 0, stream>>>(blocksums, offsets, cursor);
    fill_kernel<<<grid_edges, blk, 0, stream>>>(edge_src, edge_dst, edge_vals,
                                                cursor, edata);

    for (int layer = 0; layer < NLAYERS; ++layer) {
        float scale = (layer == NLAYERS - 1) ? (1.0f / (NLAYERS + 1)) : 1.0f;
        int write_next = (layer < NLAYERS - 1) ? 1 : 0;
        gather_kernel<<<grid_gather, blk, 0, stream>>>(
            x_cur, offsets, edata, x_next, acc, scale, write_next);
        float* tmp = x_cur; x_cur = x_next; x_next = tmp;
    }
}

// Round 8
// 620.019 us; speedup vs baseline: 8.6111x; 1.1726x over previous
//
#include <hip/hip_runtime.h>
#include <hip/hip_fp16.h>

#define NUSERS 100000
#define NITEMS 200000
#define NNODES 300000
#define DIM 64
#define NEDGES 2000000
#define SCAN_NB ((NNODES + 255) / 256)   // 1172

// Row layout (fp16): 64 halves = 128B = 16 int2. Lane l (0..15) owns int2 l
// (= dims [4l, 4l+4)).

// ---------------------------------------------------------------------------
// init: x0h = fp16(concat(user_emb, item_emb)). One float4 -> one int2(4 half)
// ---------------------------------------------------------------------------
__global__ void init_h_kernel(const float4* __restrict__ user,
                              const float4* __restrict__ item,
                              int2* __restrict__ x0h) {
    int i = blockIdx.x * blockDim.x + threadIdx.x;
    const int n_user4 = NUSERS * (DIM / 4);
    const int n4 = NNODES * (DIM / 4);
    if (i < n4) {
        float4 v = (i < n_user4) ? user[i] : item[i - n_user4];
        __half2 h01 = __floats2half2_rn(v.x, v.y);
        __half2 h23 = __floats2half2_rn(v.z, v.w);
        int2 out;
        out.x = *reinterpret_cast<int*>(&h01);
        out.y = *reinterpret_cast<int*>(&h23);
        x0h[i] = out;
    }
}

// ---------------------------------------------------------------------------
// CSR build step 1: histogram of src
// ---------------------------------------------------------------------------
__global__ void hist_kernel(const int* __restrict__ src,
                            int* __restrict__ counts) {
    int e = blockIdx.x * blockDim.x + threadIdx.x;
    if (e < NEDGES) atomicAdd(&counts[src[e]], 1);
}

// ---------------------------------------------------------------------------
// scan phase A: per-block exclusive scan of 256 counts
// ---------------------------------------------------------------------------
__global__ void scan_blocks_kernel(const int* __restrict__ counts,
                                   int* __restrict__ offsets,
                                   int* __restrict__ blocksums) {
    __shared__ int tmp[256];
    int t = threadIdx.x;
    int i = blockIdx.x * 256 + t;
    int v = (i < NNODES) ? counts[i] : 0;
    tmp[t] = v;
    __syncthreads();
    for (int off = 1; off < 256; off <<= 1) {
        int y = (t >= off) ? tmp[t - off] : 0;
        __syncthreads();
        tmp[t] += y;
        __syncthreads();
    }
    int incl = tmp[t];
    if (i < NNODES) offsets[i] = incl - v;
    if (t == 255) blocksums[blockIdx.x] = incl;
}

// ---------------------------------------------------------------------------
// scan phase B: single block exclusive-scans the SCAN_NB blocksums in place
// ---------------------------------------------------------------------------
__global__ void scan_top_kernel(int* __restrict__ blocksums) {
    __shared__ int part[256];
    __shared__ int excl[256];
    int t = threadIdx.x;
    const int chunk = (SCAN_NB + 255) / 256;
    int b0 = t * chunk;
    int b1 = b0 + chunk; if (b1 > SCAN_NB) b1 = SCAN_NB;
    int s = 0;
    for (int i = b0; i < b1; ++i) s += blocksums[i];
    part[t] = s;
    __syncthreads();
    if (t == 0) {
        int run = 0;
        for (int i = 0; i < 256; ++i) { excl[i] = run; run += part[i]; }
    }
    __syncthreads();
    int run = excl[t];
    for (int i = b0; i < b1; ++i) {
        int v = blocksums[i];
        blocksums[i] = run;
        run += v;
    }
}

// ---------------------------------------------------------------------------
// scan phase C: offsets += block base; cursor = offsets; offsets[NNODES]=NEDGES
// ---------------------------------------------------------------------------
__global__ void add_base_kernel(const int* __restrict__ blocksums,
                                int* __restrict__ offsets,
                                int* __restrict__ cursor) {
    int i = blockIdx.x * 256 + threadIdx.x;
    if (i < NNODES) {
        int o = offsets[i] + blocksums[blockIdx.x];
        offsets[i] = o;
        cursor[i] = o;
    }
    if (i == 0) offsets[NNODES] = NEDGES;
}

// ---------------------------------------------------------------------------
// CSR build step 3: scatter edges into src-sorted order (int2 {dst, valbits})
// ---------------------------------------------------------------------------
__global__ void fill_kernel(const int* __restrict__ src,
                            const int* __restrict__ dst,
                            const float* __restrict__ vals,
                            int* __restrict__ cursor,
                            int2* __restrict__ edata) {
    int e = blockIdx.x * blockDim.x + threadIdx.x;
    if (e < NEDGES) {
        int p = atomicAdd(&cursor[src[e]], 1);
        int2 ed;
        ed.x = dst[e];
        ed.y = __float_as_int(vals[e]);
        edata[p] = ed;
    }
}

// ---------------------------------------------------------------------------
// mid gather: xnexth[n] = fp16( sum over edges of fp32(xh[dst]) * val )
// 16 lanes per node; lane reads one int2 (4 halves) per edge.
// ---------------------------------------------------------------------------
__global__ void gather_mid_kernel(const int2* __restrict__ xh,
                                  const int* __restrict__ offsets,
                                  const int2* __restrict__ edata,
                                  int2* __restrict__ xnexth) {
    int t = blockIdx.x * blockDim.x + threadIdx.x;
    int n = t >> 4;
    int lane = t & 15;
    if (n >= NNODES) return;
    int b = offsets[n];
    int e1 = offsets[n + 1];
    float s0 = 0.f, s1 = 0.f, s2 = 0.f, s3 = 0.f;
    for (int e = b; e < e1; ++e) {
        int2 ed = edata[e];
        float v = __int_as_float(ed.y);
        int2 bits = xh[(size_t)ed.x * 16 + lane];
        __half2 h01 = *reinterpret_cast<__half2*>(&bits.x);
        __half2 h23 = *reinterpret_cast<__half2*>(&bits.y);
        float2 f01 = __half22float2(h01);
        float2 f23 = __half22float2(h23);
        s0 += f01.x * v; s1 += f01.y * v;
        s2 += f23.x * v; s3 += f23.y * v;
    }
    __half2 o01 = __floats2half2_rn(s0, s1);
    __half2 o23 = __floats2half2_rn(s2, s3);
    int2 out;
    out.x = *reinterpret_cast<int*>(&o01);
    out.y = *reinterpret_cast<int*>(&o23);
    xnexth[(size_t)n * 16 + lane] = out;
}

// ---------------------------------------------------------------------------
// final gather: x3sum = sum over edges of fp32(x2h[dst]) * val
// acc[n] = 0.25 * (x0h[n] + x1h[n] + x2h[n] + x3sum), written fp32 (d_out).
// ---------------------------------------------------------------------------
__device__ __forceinline__ void unpack4(int2 bits, float& a, float& b,
                                        float& c, float& d) {
    __half2 h01 = *reinterpret_cast<__half2*>(&bits.x);
    __half2 h23 = *reinterpret_cast<__half2*>(&bits.y);
    float2 f01 = __half22float2(h01);
    float2 f23 = __half22float2(h23);
    a = f01.x; b = f01.y; c = f23.x; d = f23.y;
}

__global__ void gather_final_kernel(const int2* __restrict__ x2h,
                                    const int2* __restrict__ x0h,
                                    const int2* __restrict__ x1h,
                                    const int* __restrict__ offsets,
                                    const int2* __restrict__ edata,
                                    float4* __restrict__ acc) {
    int t = blockIdx.x * blockDim.x + threadIdx.x;
    int n = t >> 4;
    int lane = t & 15;
    if (n >= NNODES) return;
    int b = offsets[n];
    int e1 = offsets[n + 1];
    float s0 = 0.f, s1 = 0.f, s2 = 0.f, s3 = 0.f;
    for (int e = b; e < e1; ++e) {
        int2 ed = edata[e];
        float v = __int_as_float(ed.y);
        int2 bits = x2h[(size_t)ed.x * 16 + lane];
        float a, bb, c, d;
        unpack4(bits, a, bb, c, d);
        s0 += a * v; s1 += bb * v; s2 += c * v; s3 += d * v;
    }
    size_t o = (size_t)n * 16 + lane;
    float a0, b0, c0, d0, a1, b1, c1, d1, a2, b2, c2, d2;
    unpack4(x0h[o], a0, b0, c0, d0);
    unpack4(x1h[o], a1, b1, c1, d1);
    unpack4(x2h[o], a2, b2, c2, d2);
    float4 r;
    r.x = 0.25f * (a0 + a1 + a2 + s0);
    r.y = 0.25f * (b0 + b1 + b2 + s1);
    r.z = 0.25f * (c0 + c1 + c2 + s2);
    r.w = 0.25f * (d0 + d1 + d2 + s3);
    acc[o] = r;
}

extern "C" void kernel_launch(void* const* d_in, const int* in_sizes, int n_in,
                              void* d_out, int out_size, void* d_ws, size_t ws_size,
                              hipStream_t stream) {
    const float* user_emb = (const float*)d_in[0];
    const float* item_emb = (const float*)d_in[1];
    const float* edge_vals = (const float*)d_in[2];
    const int* edge_src = (const int*)d_in[3];
    const int* edge_dst = (const int*)d_in[4];
    float4* acc = (float4*)d_out;

    // ---- workspace layout (bytes) ----
    const size_t xh_bytes = (size_t)NNODES * DIM * 2;   // 38.4 MB
    char* ws = (char*)d_ws;
    int2* x0h      = (int2*)(ws);
    int2* x1h      = (int2*)(ws + xh_bytes);
    int2* x2h      = (int2*)(ws + 2 * xh_bytes);
    char* p        = ws + 3 * xh_bytes;
    int* offsets   = (int*)p;                 p += (size_t)(NNODES + 1) * 4 + 12;
    int* cursor    = (int*)p;                 p += (size_t)NNODES * 4;
    int* blocksums = (int*)p;                 p += (size_t)SCAN_NB * 4 + 16;
    int2* edata    = (int2*)p;                // 16 MB
    // counts aliases edata (dead before edata is written by fill)
    int* counts    = (int*)edata;

    const int n4 = NNODES * (DIM / 4);
    dim3 blk(256);
    dim3 grid_nodes4((n4 + 255) / 256);
    dim3 grid_edges((NEDGES + 255) / 256);
    dim3 grid_scan(SCAN_NB);
    dim3 grid_gather((NNODES * 16 + 255) / 256);

    init_h_kernel<<<grid_nodes4, blk, 0, stream>>>(
        (const float4*)user_emb, (const float4*)item_emb, x0h);

    hipMemsetAsync(counts, 0, (size_t)NNODES * sizeof(int), stream);
    hist_kernel<<<grid_edges, blk, 0, stream>>>(edge_src, counts);
    scan_blocks_kernel<<<grid_scan, blk, 0, stream>>>(counts, offsets, blocksums);
    scan_top_kernel<<<1, blk, 0, stream>>>(blocksums);
    add_base_kernel<<<grid_scan, blk, 0, stream>>>(blocksums, offsets, cursor);
    fill_kernel<<<grid_edges, blk, 0, stream>>>(edge_src, edge_dst, edge_vals,
                                                cursor, edata);

    gather_mid_kernel<<<grid_gather, blk, 0, stream>>>(x0h, offsets, edata, x1h);
    gather_mid_kernel<<<grid_gather, blk, 0, stream>>>(x1h, offsets, edata, x2h);
    gather_final_kernel<<<grid_gather, blk, 0, stream>>>(x2h, x0h, x1h,
                                                         offsets, edata, acc);
}

// Round 9
// 531.563 us; speedup vs baseline: 10.0441x; 1.1664x over previous
//
#include <hip/hip_runtime.h>
#include <hip/hip_fp16.h>

#define NUSERS 100000
#define NITEMS 200000
#define NNODES 300000
#define DIM 64
#define NEDGES 2000000

#define BSHIFT 5
#define NBUCK (NNODES >> BSHIFT)          // 9375 buckets of 32 nodes
#define BCAP 320                          // mean 213, sigma 14.6 -> +7.3 sigma
#define GB 8                              // buckets per 256-node group
#define NGROUP ((NNODES + 255) / 256)     // 1172
#define GCAP (GB * BCAP)                  // 2560 slots per group region

// Row layout (fp16): 64 halves = 128B = 16 int2. Lane l (0..15) owns int2 l.

// ---------------------------------------------------------------------------
// init: x0h = fp16(concat(user_emb, item_emb))
// ---------------------------------------------------------------------------
__global__ void init_h_kernel(const float4* __restrict__ user,
                              const float4* __restrict__ item,
                              int2* __restrict__ x0h) {
    int i = blockIdx.x * blockDim.x + threadIdx.x;
    const int n_user4 = NUSERS * (DIM / 4);
    const int n4 = NNODES * (DIM / 4);
    if (i < n4) {
        float4 v = (i < n_user4) ? user[i] : item[i - n_user4];
        __half2 h01 = __floats2half2_rn(v.x, v.y);
        __half2 h23 = __floats2half2_rn(v.z, v.w);
        int2 out;
        out.x = *reinterpret_cast<int*>(&h01);
        out.y = *reinterpret_cast<int*>(&h23);
        x0h[i] = out;
    }
}

// ---------------------------------------------------------------------------
// stage: append edge to its src-bucket's fixed-capacity region.
// Consecutive atomic slots => write-combined lines (active set ~600KB).
// Packed: .x = dst | (src&255)<<19  (dst < 2^19), .y = val bits.
// ---------------------------------------------------------------------------
__global__ void stage_kernel(const int* __restrict__ src,
                             const int* __restrict__ dst,
                             const float* __restrict__ vals,
                             int* __restrict__ bcursor,
                             int2* __restrict__ staged) {
    int e = blockIdx.x * blockDim.x + threadIdx.x;
    if (e < NEDGES) {
        int s = src[e];
        int b = s >> BSHIFT;
        int p = atomicAdd(&bcursor[b], 1);
        int2 ed;
        ed.x = dst[e] | ((s & 255) << 19);
        ed.y = __float_as_int(vals[e]);
        staged[(size_t)b * BCAP + p] = ed;
    }
}

// ---------------------------------------------------------------------------
// finalize: one WG per 256-node group (= GB buckets). LDS node-histogram ->
// LDS scan -> per-node {begin,end} ranges -> replay staged edges into
// node-sorted order within the group's fixed GCAP region.
// ---------------------------------------------------------------------------
__global__ void finalize_kernel(const int* __restrict__ bcursor,
                                const int2* __restrict__ staged,
                                int2* __restrict__ edata,
                                int2* __restrict__ range) {
    __shared__ int cnt[256];
    __shared__ int tmp[256];
    __shared__ int cur[256];
    __shared__ int bcnt[GB];
    int g = blockIdx.x;
    int t = threadIdx.x;
    int b0 = g * GB;
    cnt[t] = 0;
    if (t < GB) {
        int b = b0 + t;
        bcnt[t] = (b < NBUCK) ? bcursor[b] : 0;
    }
    __syncthreads();
    // per-node histogram (src low 8 bits == node index within group)
    for (int k = 0; k < GB; ++k) {
        int c = bcnt[k];
        const int2* sp = staged + (size_t)(b0 + k) * BCAP;
        for (int i = t; i < c; i += 256) {
            int slow = ((unsigned)sp[i].x) >> 19;
            atomicAdd(&cnt[slow], 1);
        }
    }
    __syncthreads();
    // exclusive scan of cnt
    int v = cnt[t];
    tmp[t] = v;
    __syncthreads();
    for (int off = 1; off < 256; off <<= 1) {
        int y = (t >= off) ? tmp[t - off] : 0;
        __syncthreads();
        tmp[t] += y;
        __syncthreads();
    }
    int excl = tmp[t] - v;
    int gbase = g * GCAP;
    int n = g * 256 + t;
    if (n < NNODES) {
        int2 r;
        r.x = gbase + excl;
        r.y = gbase + excl + v;
        range[n] = r;
    }
    cur[t] = excl;
    __syncthreads();
    // replay into node-sorted positions (writes confined to ~20KB window)
    for (int k = 0; k < GB; ++k) {
        int c = bcnt[k];
        const int2* sp = staged + (size_t)(b0 + k) * BCAP;
        for (int i = t; i < c; i += 256) {
            int2 ed = sp[i];
            int slow = ((unsigned)ed.x) >> 19;
            int q = atomicAdd(&cur[slow], 1);
            int2 out;
            out.x = ed.x & 0x7FFFF;
            out.y = ed.y;
            edata[(size_t)gbase + q] = out;
        }
    }
}

// ---------------------------------------------------------------------------
// mid gather: xnexth[n] = fp16( sum over edges of fp32(xh[dst]) * val )
// ---------------------------------------------------------------------------
__global__ void gather_mid_kernel(const int2* __restrict__ xh,
                                  const int2* __restrict__ range,
                                  const int2* __restrict__ edata,
                                  int2* __restrict__ xnexth) {
    int t = blockIdx.x * blockDim.x + threadIdx.x;
    int n = t >> 4;
    int lane = t & 15;
    if (n >= NNODES) return;
    int2 r = range[n];
    float s0 = 0.f, s1 = 0.f, s2 = 0.f, s3 = 0.f;
    for (int e = r.x; e < r.y; ++e) {
        int2 ed = edata[e];
        float v = __int_as_float(ed.y);
        int2 bits = xh[(size_t)ed.x * 16 + lane];
        __half2 h01 = *reinterpret_cast<__half2*>(&bits.x);
        __half2 h23 = *reinterpret_cast<__half2*>(&bits.y);
        float2 f01 = __half22float2(h01);
        float2 f23 = __half22float2(h23);
        s0 += f01.x * v; s1 += f01.y * v;
        s2 += f23.x * v; s3 += f23.y * v;
    }
    __half2 o01 = __floats2half2_rn(s0, s1);
    __half2 o23 = __floats2half2_rn(s2, s3);
    int2 out;
    out.x = *reinterpret_cast<int*>(&o01);
    out.y = *reinterpret_cast<int*>(&o23);
    xnexth[(size_t)n * 16 + lane] = out;
}

// ---------------------------------------------------------------------------
// final gather: acc[n] = 0.25*(x0h+x1h+x2h + sum fp32(x2h[dst])*val), fp32 out
// ---------------------------------------------------------------------------
__device__ __forceinline__ void unpack4(int2 bits, float& a, float& b,
                                        float& c, float& d) {
    __half2 h01 = *reinterpret_cast<__half2*>(&bits.x);
    __half2 h23 = *reinterpret_cast<__half2*>(&bits.y);
    float2 f01 = __half22float2(h01);
    float2 f23 = __half22float2(h23);
    a = f01.x; b = f01.y; c = f23.x; d = f23.y;
}

__global__ void gather_final_kernel(const int2* __restrict__ x2h,
                                    const int2* __restrict__ x0h,
                                    const int2* __restrict__ x1h,
                                    const int2* __restrict__ range,
                                    const int2* __restrict__ edata,
                                    float4* __restrict__ acc) {
    int t = blockIdx.x * blockDim.x + threadIdx.x;
    int n = t >> 4;
    int lane = t & 15;
    if (n >= NNODES) return;
    int2 r = range[n];
    float s0 = 0.f, s1 = 0.f, s2 = 0.f, s3 = 0.f;
    for (int e = r.x; e < r.y; ++e) {
        int2 ed = edata[e];
        float v = __int_as_float(ed.y);
        int2 bits = x2h[(size_t)ed.x * 16 + lane];
        float a, bb, c, d;
        unpack4(bits, a, bb, c, d);
        s0 += a * v; s1 += bb * v; s2 += c * v; s3 += d * v;
    }
    size_t o = (size_t)n * 16 + lane;
    float a0, b0, c0, d0, a1, b1, c1, d1, a2, b2, c2, d2;
    unpack4(x0h[o], a0, b0, c0, d0);
    unpack4(x1h[o], a1, b1, c1, d1);
    unpack4(x2h[o], a2, b2, c2, d2);
    float4 rr;
    rr.x = 0.25f * (a0 + a1 + a2 + s0);
    rr.y = 0.25f * (b0 + b1 + b2 + s1);
    rr.z = 0.25f * (c0 + c1 + c2 + s2);
    rr.w = 0.25f * (d0 + d1 + d2 + s3);
    acc[o] = rr;
}

extern "C" void kernel_launch(void* const* d_in, const int* in_sizes, int n_in,
                              void* d_out, int out_size, void* d_ws, size_t ws_size,
                              hipStream_t stream) {
    const float* user_emb = (const float*)d_in[0];
    const float* item_emb = (const float*)d_in[1];
    const float* edge_vals = (const float*)d_in[2];
    const int* edge_src = (const int*)d_in[3];
    const int* edge_dst = (const int*)d_in[4];
    float4* acc = (float4*)d_out;

    // ---- workspace layout (bytes) ----
    const size_t xh_bytes = (size_t)NNODES * DIM * 2;          // 38.4 MB
    char* ws = (char*)d_ws;
    int2* x0h     = (int2*)(ws);
    int2* x1h     = (int2*)(ws + xh_bytes);
    int2* x2h     = (int2*)(ws + 2 * xh_bytes);
    char* p       = ws + 3 * xh_bytes;
    int2* range   = (int2*)p;   p += (size_t)NNODES * 8;       // 2.4 MB
    int* bcursor  = (int*)p;    p += (size_t)NBUCK * 4 + 16;   // 37.5 KB
    int2* staged  = (int2*)p;   p += (size_t)NBUCK * BCAP * 8; // 24 MB
    int2* edata   = (int2*)p;                                  // 24 MB

    const int n4 = NNODES * (DIM / 4);
    dim3 blk(256);
    dim3 grid_nodes4((n4 + 255) / 256);
    dim3 grid_edges((NEDGES + 255) / 256);
    dim3 grid_groups(NGROUP);
    dim3 grid_gather((NNODES * 16 + 255) / 256);

    init_h_kernel<<<grid_nodes4, blk, 0, stream>>>(
        (const float4*)user_emb, (const float4*)item_emb, x0h);

    hipMemsetAsync(bcursor, 0, (size_t)NBUCK * sizeof(int), stream);
    stage_kernel<<<grid_edges, blk, 0, stream>>>(edge_src, edge_dst, edge_vals,
                                                 bcursor, staged);
    finalize_kernel<<<grid_groups, blk, 0, stream>>>(bcursor, staged,
                                                     edata, range);

    gather_mid_kernel<<<grid_gather, blk, 0, stream>>>(x0h, range, edata, x1h);
    gather_mid_kernel<<<grid_gather, blk, 0, stream>>>(x1h, range, edata, x2h);
    gather_final_kernel<<<grid_gather, blk, 0, stream>>>(x2h, x0h, x1h,
                                                         range, edata, acc);
}